// Round 10
// baseline (483.606 us; speedup 1.0000x reference)
//
#include <hip/hip_runtime.h>
#include <math.h>

// Problem constants
#define HID 4096
#define NH  32
#define NKV 8
#define DH  128
#define SEQ 64
#define BS  16
#define MC  1024
#define QKV_N 6144                 // (NH + 2*NKV) * DH
#define NPAGES 64                  // MC / BS
#define KC  64                     // GEMM K-chunk (LDS tile depth)
#define KS  4                      // GEMM K-split factor
#define GQ  4                      // NH / NKV
#define CSPLIT 4                   // attention context splits
#define TPS (MC / CSPLIT)          // 256 tokens per split
#define NHQ (SEQ * NH)             // 2048 (s,qhead) pairs

// Static device scratch (BSS) — immune to ws_size.
__device__ float g_qkv[SEQ * QKV_N];            // 1.5 MB
__device__ float g_attn[SEQ * HID];             // 1.0 MB
__device__ float g_part[KS * SEQ * QKV_N];      // 6.3 MB (GEMM partials / attn o-partials)
__device__ float g_pm[CSPLIT * NHQ];            // split max
__device__ float g_pl[CSPLIT * NHQ];            // split sum

// ---------------------------------------------------------------------------
// Tiled GEMM with K-split (unchanged from R8 — verified).
// ---------------------------------------------------------------------------
__global__ __launch_bounds__(256) void gemm_tile(const float* __restrict__ X,
                                                 const float* __restrict__ W,
                                                 float* __restrict__ P,
                                                 int N, int K) {
    __shared__ float Xs[KC][68];
    __shared__ float Ws[KC][68];
    const int tid = threadIdx.x;
    const int tx = tid & 15;
    const int ty = tid >> 4;
    const int jb = blockIdx.x * 64;
    const int ks = blockIdx.y;
    const int k_lo = ks * (K / KS);
    const int k_hi = k_lo + (K / KS);

    float4 a0 = {0,0,0,0}, a1 = {0,0,0,0}, a2 = {0,0,0,0}, a3 = {0,0,0,0};

    for (int k0 = k_lo; k0 < k_hi; k0 += KC) {
        #pragma unroll
        for (int r = 0; r < 4; ++r) {
            int idx = r * 256 + tid;
            int s  = idx >> 4;
            int k4 = idx & 15;
            float4 v = *(const float4*)(X + (size_t)s * K + k0 + k4 * 4);
            Xs[k4 * 4 + 0][s] = v.x;
            Xs[k4 * 4 + 1][s] = v.y;
            Xs[k4 * 4 + 2][s] = v.z;
            Xs[k4 * 4 + 3][s] = v.w;
        }
        #pragma unroll
        for (int r = 0; r < 4; ++r) {
            int idx = r * 256 + tid;
            int j  = idx >> 4;
            int k4 = idx & 15;
            float4 v = *(const float4*)(W + (size_t)(jb + j) * K + k0 + k4 * 4);
            Ws[k4 * 4 + 0][j] = v.x;
            Ws[k4 * 4 + 1][j] = v.y;
            Ws[k4 * 4 + 2][j] = v.z;
            Ws[k4 * 4 + 3][j] = v.w;
        }
        __syncthreads();
        #pragma unroll
        for (int kk = 0; kk < KC; ++kk) {
            float4 xv = *(const float4*)(&Xs[kk][ty * 4]);
            float4 wv = *(const float4*)(&Ws[kk][tx * 4]);
            a0.x = fmaf(xv.x, wv.x, a0.x); a0.y = fmaf(xv.x, wv.y, a0.y);
            a0.z = fmaf(xv.x, wv.z, a0.z); a0.w = fmaf(xv.x, wv.w, a0.w);
            a1.x = fmaf(xv.y, wv.x, a1.x); a1.y = fmaf(xv.y, wv.y, a1.y);
            a1.z = fmaf(xv.y, wv.z, a1.z); a1.w = fmaf(xv.y, wv.w, a1.w);
            a2.x = fmaf(xv.z, wv.x, a2.x); a2.y = fmaf(xv.z, wv.y, a2.y);
            a2.z = fmaf(xv.z, wv.z, a2.z); a2.w = fmaf(xv.z, wv.w, a2.w);
            a3.x = fmaf(xv.w, wv.x, a3.x); a3.y = fmaf(xv.w, wv.y, a3.y);
            a3.z = fmaf(xv.w, wv.z, a3.z); a3.w = fmaf(xv.w, wv.w, a3.w);
        }
        __syncthreads();
    }
    float* pb = P + (size_t)ks * SEQ * N;
    *(float4*)(pb + (size_t)(ty * 4 + 0) * N + jb + tx * 4) = a0;
    *(float4*)(pb + (size_t)(ty * 4 + 1) * N + jb + tx * 4) = a1;
    *(float4*)(pb + (size_t)(ty * 4 + 2) * N + jb + tx * 4) = a2;
    *(float4*)(pb + (size_t)(ty * 4 + 3) * N + jb + tx * 4) = a3;
}

__global__ __launch_bounds__(256) void reduce_ks(const float* __restrict__ P,
                                                 float* __restrict__ Y, int n4) {
    int t = blockIdx.x * 256 + threadIdx.x;
    if (t >= n4) return;
    const float4* p4 = (const float4*)P;
    float4 a = p4[t];
    float4 b = p4[t + n4];
    float4 c = p4[t + 2 * n4];
    float4 d = p4[t + 3 * n4];
    float4 r;
    r.x = (a.x + b.x) + (c.x + d.x);
    r.y = (a.y + b.y) + (c.y + d.y);
    r.z = (a.z + b.z) + (c.z + d.z);
    r.w = (a.w + b.w) + (c.w + d.w);
    ((float4*)Y)[t] = r;
}

// ---------------------------------------------------------------------------
// Scalar RoPE (unchanged, verified). sincosf(x, &sin, &cos) — sin FIRST.
// ---------------------------------------------------------------------------
__global__ __launch_bounds__(256) void rope_scalar(float* __restrict__ qkv,
                                                   const int* __restrict__ ia,
                                                   const int* __restrict__ ib) {
    int t = blockIdx.x * 256 + threadIdx.x;
    if (t >= SEQ * (NH + NKV) * 64) return;
    int i = t & 63;
    int h = (t >> 6) % (NH + NKV);
    int s = t / ((NH + NKV) * 64);
    int pos = max(ia[s], ib[s]) - 1;
    float* base = qkv + (size_t)s * QKV_N + (size_t)h * DH;
    float ang = (float)pos / powf(10000.0f, (float)i * 2.0f / (float)DH);
    float sn, c;
    sincosf(ang, &sn, &c);
    float x1 = base[i];
    float x2 = base[i + 64];
    base[i]      = x1 * c - x2 * sn;
    base[i + 64] = x2 * c + x1 * sn;
}

// ---------------------------------------------------------------------------
// Flash-decode attention, pass 1: block per (s, kv, split). 4 waves = 4 q heads.
// Each split handles tokens [t*256, min((t+1)*256, L)). Unnormalized partial
// o plus (m, l) written to scratch. New-token K/V: read-time override.
// ---------------------------------------------------------------------------
__global__ __launch_bounds__(256) void attn_split(const float* __restrict__ qkv,
                                                  const float* __restrict__ k_cache,
                                                  const float* __restrict__ v_cache,
                                                  const int* __restrict__ ia,
                                                  const int* __restrict__ ib,
                                                  const int* __restrict__ block_tables,
                                                  float* __restrict__ po,
                                                  float* __restrict__ pm,
                                                  float* __restrict__ pl) {
    __shared__ float sc[GQ][TPS];   // 4 KB
    __shared__ float qs[GQ][DH];    // 2 KB

    int b  = blockIdx.x;
    int t  = b & 3;                 // split
    int kv = (b >> 2) & 7;
    int s  = b >> 5;
    int tid = threadIdx.x;
    int lane = tid & 63;
    int g = tid >> 6;

    int L   = max(ia[s], ib[s]);
    int pos = L - 1;
    int c_lo = t * TPS;
    int c_hi = min(c_lo + TPS, L);
    int n = c_hi - c_lo;            // may be <= 0 (empty split)

    for (int i = tid; i < GQ * DH; i += 256)
        qs[i >> 7][i & 127] = qkv[(size_t)s * QKV_N + (size_t)(kv * GQ) * DH + i]
                              * 0.08838834764831845f;
    __syncthreads();

    const float* knew = qkv + (size_t)s * QKV_N + (size_t)NH * DH + (size_t)kv * DH;
    const float* vnew = qkv + (size_t)s * QKV_N + (size_t)(NH + NKV) * DH + (size_t)kv * DH;
    const int* bt = block_tables + s * NPAGES;
    const float4* q4 = (const float4*)qs[g];

    // Phase 1: scores (lane-per-token, float4 dot from global; waves share rows via L1)
    for (int c = c_lo + lane; c < c_hi; c += 64) {
        const float* kr = (c == pos)
            ? knew
            : k_cache + ((size_t)bt[c >> 4] * BS + (c & 15)) * (size_t)(NKV * DH)
                      + (size_t)kv * DH;
        const float4* k4 = (const float4*)kr;
        float aa = 0.f, bb = 0.f, cc = 0.f, dd = 0.f;
        #pragma unroll
        for (int i = 0; i < 32; i += 4) {
            float4 k0 = k4[i], k1 = k4[i + 1], k2 = k4[i + 2], k3 = k4[i + 3];
            float4 q0 = q4[i], q1 = q4[i + 1], q2 = q4[i + 2], q3 = q4[i + 3];
            aa += q0.x * k0.x + q0.y * k0.y + q0.z * k0.z + q0.w * k0.w;
            bb += q1.x * k1.x + q1.y * k1.y + q1.z * k1.z + q1.w * k1.w;
            cc += q2.x * k2.x + q2.y * k2.y + q2.z * k2.z + q2.w * k2.w;
            dd += q3.x * k3.x + q3.y * k3.y + q3.z * k3.z + q3.w * k3.w;
        }
        sc[g][c - c_lo] = (aa + bb) + (cc + dd);
    }
    __syncthreads();   // order sc writes vs reads (cheap, safe)

    // Phase 2: wave softmax over sc[g][0..n)
    float m = -1e30f;
    for (int c = lane; c < n; c += 64) m = fmaxf(m, sc[g][c]);
    #pragma unroll
    for (int off = 32; off; off >>= 1) m = fmaxf(m, __shfl_xor(m, off, 64));
    float l = 0.f;
    for (int c = lane; c < n; c += 64) {
        float p = expf(sc[g][c] - m);
        sc[g][c] = p;
        l += p;
    }
    #pragma unroll
    for (int off = 32; off; off >>= 1) l += __shfl_xor(l, off, 64);
    __syncthreads();

    // Phase 3: unnormalized PV; lane owns dims (2*lane, 2*lane+1)
    float a0 = 0.f, a1 = 0.f, b0 = 0.f, b1 = 0.f;
    float c0 = 0.f, c1 = 0.f, e0 = 0.f, e1 = 0.f;
    int c = 0;
    for (; c + 3 < n; c += 4) {
        int cc0 = c_lo + c, cc1 = c_lo + c + 1, cc2 = c_lo + c + 2, cc3 = c_lo + c + 3;
        const float* v0p = (cc0 == pos) ? vnew : v_cache + ((size_t)bt[cc0 >> 4] * BS + (cc0 & 15)) * (size_t)(NKV * DH) + (size_t)kv * DH;
        const float* v1p = (cc1 == pos) ? vnew : v_cache + ((size_t)bt[cc1 >> 4] * BS + (cc1 & 15)) * (size_t)(NKV * DH) + (size_t)kv * DH;
        const float* v2p = (cc2 == pos) ? vnew : v_cache + ((size_t)bt[cc2 >> 4] * BS + (cc2 & 15)) * (size_t)(NKV * DH) + (size_t)kv * DH;
        const float* v3p = (cc3 == pos) ? vnew : v_cache + ((size_t)bt[cc3 >> 4] * BS + (cc3 & 15)) * (size_t)(NKV * DH) + (size_t)kv * DH;
        float p0 = sc[g][c], p1 = sc[g][c + 1], p2 = sc[g][c + 2], p3 = sc[g][c + 3];
        float2 v0 = ((const float2*)v0p)[lane];
        float2 v1 = ((const float2*)v1p)[lane];
        float2 v2 = ((const float2*)v2p)[lane];
        float2 v3 = ((const float2*)v3p)[lane];
        a0 = fmaf(p0, v0.x, a0); a1 = fmaf(p0, v0.y, a1);
        b0 = fmaf(p1, v1.x, b0); b1 = fmaf(p1, v1.y, b1);
        c0 = fmaf(p2, v2.x, c0); c1 = fmaf(p2, v2.y, c1);
        e0 = fmaf(p3, v3.x, e0); e1 = fmaf(p3, v3.y, e1);
    }
    for (; c < n; ++c) {
        int cc0 = c_lo + c;
        const float* vp = (cc0 == pos) ? vnew : v_cache + ((size_t)bt[cc0 >> 4] * BS + (cc0 & 15)) * (size_t)(NKV * DH) + (size_t)kv * DH;
        float p = sc[g][c];
        float2 v = ((const float2*)vp)[lane];
        a0 = fmaf(p, v.x, a0); a1 = fmaf(p, v.y, a1);
    }
    float o0 = (a0 + b0) + (c0 + e0);
    float o1 = (a1 + b1) + (c1 + e1);

    int hq = kv * GQ + g;                          // q head index
    int idx = t * NHQ + s * NH + hq;
    float* ob = po + (size_t)idx * DH;
    ob[2 * lane]     = o0;
    ob[2 * lane + 1] = o1;
    if (lane == 0) {
        pm[idx] = (n > 0) ? m : -1e30f;
        pl[idx] = (n > 0) ? l : 0.f;
    }
}

// ---------------------------------------------------------------------------
// Flash-decode combine: block per (s,qh) [2048], thread per dim [128].
// ---------------------------------------------------------------------------
__global__ __launch_bounds__(128) void attn_combine(const float* __restrict__ po,
                                                    const float* __restrict__ pm,
                                                    const float* __restrict__ pl,
                                                    float* __restrict__ attn_out) {
    int sh = blockIdx.x;       // s*NH + qh
    int d  = threadIdx.x;
    float m0 = pm[0 * NHQ + sh], m1 = pm[1 * NHQ + sh];
    float m2 = pm[2 * NHQ + sh], m3 = pm[3 * NHQ + sh];
    float M = fmaxf(fmaxf(m0, m1), fmaxf(m2, m3));
    float w0 = expf(m0 - M), w1 = expf(m1 - M);
    float w2 = expf(m2 - M), w3 = expf(m3 - M);
    float denom = pl[0 * NHQ + sh] * w0 + pl[1 * NHQ + sh] * w1
                + pl[2 * NHQ + sh] * w2 + pl[3 * NHQ + sh] * w3;
    float num = po[(size_t)(0 * NHQ + sh) * DH + d] * w0
              + po[(size_t)(1 * NHQ + sh) * DH + d] * w1
              + po[(size_t)(2 * NHQ + sh) * DH + d] * w2
              + po[(size_t)(3 * NHQ + sh) * DH + d] * w3;
    attn_out[(size_t)sh * DH + d] = num / denom;
}

// ---------------------------------------------------------------------------
extern "C" void kernel_launch(void* const* d_in, const int* in_sizes, int n_in,
                              void* d_out, int out_size, void* d_ws, size_t ws_size,
                              hipStream_t stream) {
    const float *hidden = nullptr, *k_cache = nullptr, *v_cache = nullptr;
    const float *qkv_w = nullptr, *o_w = nullptr;
    const int *i64a = nullptr, *i64b = nullptr, *block_tables = nullptr;
    for (int i = 0; i < n_in; ++i) {
        switch (in_sizes[i]) {
            case SEQ * HID:          hidden = (const float*)d_in[i]; break;
            case 4096 * BS * NKV * DH:
                if (!k_cache) k_cache = (const float*)d_in[i];
                else          v_cache = (const float*)d_in[i];
                break;
            case QKV_N * HID:        qkv_w = (const float*)d_in[i]; break;
            case HID * HID:          o_w   = (const float*)d_in[i]; break;
            case SEQ * NPAGES:       block_tables = (const int*)d_in[i]; break;
            case SEQ:
                if (!i64a) i64a = (const int*)d_in[i];
                else       i64b = (const int*)d_in[i];
                break;
        }
    }
    float* out = (float*)d_out;

    static float* qkv_p  = nullptr;
    static float* attn_p = nullptr;
    static float* part_p = nullptr;
    static float* pm_p   = nullptr;
    static float* pl_p   = nullptr;
    if (!qkv_p) {
        void* p;
        hipGetSymbolAddress(&p, HIP_SYMBOL(g_qkv));  qkv_p  = (float*)p;
        hipGetSymbolAddress(&p, HIP_SYMBOL(g_attn)); attn_p = (float*)p;
        hipGetSymbolAddress(&p, HIP_SYMBOL(g_part)); part_p = (float*)p;
        hipGetSymbolAddress(&p, HIP_SYMBOL(g_pm));   pm_p   = (float*)p;
        hipGetSymbolAddress(&p, HIP_SYMBOL(g_pl));   pl_p   = (float*)p;
    }

    // 1) QKV projection
    gemm_tile<<<dim3(QKV_N / 64, KS), 256, 0, stream>>>(hidden, qkv_w, part_p,
                                                        QKV_N, HID);
    reduce_ks<<<(SEQ * QKV_N / 4 + 255) / 256, 256, 0, stream>>>(part_p, qkv_p,
                                                                 SEQ * QKV_N / 4);
    // 2) RoPE
    rope_scalar<<<(SEQ * (NH + NKV) * 64) / 256, 256, 0, stream>>>(qkv_p, i64a, i64b);
    // 3) Flash-decode attention
    attn_split<<<SEQ * NKV * CSPLIT, 256, 0, stream>>>(qkv_p, k_cache, v_cache,
                                                       i64a, i64b, block_tables,
                                                       part_p, pm_p, pl_p);
    attn_combine<<<NHQ, 128, 0, stream>>>(part_p, pm_p, pl_p, attn_p);
    // 4) Output projection
    gemm_tile<<<dim3(HID / 64, KS), 256, 0, stream>>>(attn_p, o_w, part_p,
                                                      HID, HID);
    reduce_ks<<<(SEQ * HID / 4 + 255) / 256, 256, 0, stream>>>(part_p, out,
                                                               SEQ * HID / 4);
}

// Round 11
// 384.789 us; speedup vs baseline: 1.2568x; 1.2568x over previous
//
#include <hip/hip_runtime.h>
#include <math.h>

// Problem constants
#define HID 4096
#define NH  32
#define NKV 8
#define DH  128
#define SEQ 64
#define BS  16
#define MC  1024
#define QKV_N 6144                 // (NH + 2*NKV) * DH
#define NPAGES 64                  // MC / BS
#define KC  64                     // GEMM K-chunk (LDS tile depth)
#define KS  4                      // GEMM K-split factor
#define GQ  4                      // NH / NKV
#define CSPLIT 8                   // attention context splits (dynamic ranges)
#define TPS 128                    // max tokens per split (ceil(1024/8))
#define NHQ (SEQ * NH)             // 2048 (s,qhead) pairs

// Static device scratch (BSS) — immune to ws_size.
__device__ float g_qkv[SEQ * QKV_N];            // 1.5 MB
__device__ float g_attn[SEQ * HID];             // 1.0 MB
__device__ float g_part[KS * SEQ * QKV_N];      // 6.3 MB (GEMM partials)
__device__ float g_po[CSPLIT * NHQ * DH];       // 8.0 MB (attn o-partials)
__device__ float g_pm[CSPLIT * NHQ];            // split max
__device__ float g_pl[CSPLIT * NHQ];            // split sum

// ---------------------------------------------------------------------------
// Tiled GEMM with K-split (unchanged, verified).
// ---------------------------------------------------------------------------
__global__ __launch_bounds__(256) void gemm_tile(const float* __restrict__ X,
                                                 const float* __restrict__ W,
                                                 float* __restrict__ P,
                                                 int N, int K) {
    __shared__ float Xs[KC][68];
    __shared__ float Ws[KC][68];
    const int tid = threadIdx.x;
    const int tx = tid & 15;
    const int ty = tid >> 4;
    const int jb = blockIdx.x * 64;
    const int ks = blockIdx.y;
    const int k_lo = ks * (K / KS);
    const int k_hi = k_lo + (K / KS);

    float4 a0 = {0,0,0,0}, a1 = {0,0,0,0}, a2 = {0,0,0,0}, a3 = {0,0,0,0};

    for (int k0 = k_lo; k0 < k_hi; k0 += KC) {
        #pragma unroll
        for (int r = 0; r < 4; ++r) {
            int idx = r * 256 + tid;
            int s  = idx >> 4;
            int k4 = idx & 15;
            float4 v = *(const float4*)(X + (size_t)s * K + k0 + k4 * 4);
            Xs[k4 * 4 + 0][s] = v.x;
            Xs[k4 * 4 + 1][s] = v.y;
            Xs[k4 * 4 + 2][s] = v.z;
            Xs[k4 * 4 + 3][s] = v.w;
        }
        #pragma unroll
        for (int r = 0; r < 4; ++r) {
            int idx = r * 256 + tid;
            int j  = idx >> 4;
            int k4 = idx & 15;
            float4 v = *(const float4*)(W + (size_t)(jb + j) * K + k0 + k4 * 4);
            Ws[k4 * 4 + 0][j] = v.x;
            Ws[k4 * 4 + 1][j] = v.y;
            Ws[k4 * 4 + 2][j] = v.z;
            Ws[k4 * 4 + 3][j] = v.w;
        }
        __syncthreads();
        #pragma unroll
        for (int kk = 0; kk < KC; ++kk) {
            float4 xv = *(const float4*)(&Xs[kk][ty * 4]);
            float4 wv = *(const float4*)(&Ws[kk][tx * 4]);
            a0.x = fmaf(xv.x, wv.x, a0.x); a0.y = fmaf(xv.x, wv.y, a0.y);
            a0.z = fmaf(xv.x, wv.z, a0.z); a0.w = fmaf(xv.x, wv.w, a0.w);
            a1.x = fmaf(xv.y, wv.x, a1.x); a1.y = fmaf(xv.y, wv.y, a1.y);
            a1.z = fmaf(xv.y, wv.z, a1.z); a1.w = fmaf(xv.y, wv.w, a1.w);
            a2.x = fmaf(xv.z, wv.x, a2.x); a2.y = fmaf(xv.z, wv.y, a2.y);
            a2.z = fmaf(xv.z, wv.z, a2.z); a2.w = fmaf(xv.z, wv.w, a2.w);
            a3.x = fmaf(xv.w, wv.x, a3.x); a3.y = fmaf(xv.w, wv.y, a3.y);
            a3.z = fmaf(xv.w, wv.z, a3.z); a3.w = fmaf(xv.w, wv.w, a3.w);
        }
        __syncthreads();
    }
    float* pb = P + (size_t)ks * SEQ * N;
    *(float4*)(pb + (size_t)(ty * 4 + 0) * N + jb + tx * 4) = a0;
    *(float4*)(pb + (size_t)(ty * 4 + 1) * N + jb + tx * 4) = a1;
    *(float4*)(pb + (size_t)(ty * 4 + 2) * N + jb + tx * 4) = a2;
    *(float4*)(pb + (size_t)(ty * 4 + 3) * N + jb + tx * 4) = a3;
}

__global__ __launch_bounds__(256) void reduce_ks(const float* __restrict__ P,
                                                 float* __restrict__ Y, int n4) {
    int t = blockIdx.x * 256 + threadIdx.x;
    if (t >= n4) return;
    const float4* p4 = (const float4*)P;
    float4 a = p4[t];
    float4 b = p4[t + n4];
    float4 c = p4[t + 2 * n4];
    float4 d = p4[t + 3 * n4];
    float4 r;
    r.x = (a.x + b.x) + (c.x + d.x);
    r.y = (a.y + b.y) + (c.y + d.y);
    r.z = (a.z + b.z) + (c.z + d.z);
    r.w = (a.w + b.w) + (c.w + d.w);
    ((float4*)Y)[t] = r;
}

// ---------------------------------------------------------------------------
// Scalar RoPE (unchanged, verified). sincosf(x, &sin, &cos) — sin FIRST.
// ---------------------------------------------------------------------------
__global__ __launch_bounds__(256) void rope_scalar(float* __restrict__ qkv,
                                                   const int* __restrict__ ia,
                                                   const int* __restrict__ ib) {
    int t = blockIdx.x * 256 + threadIdx.x;
    if (t >= SEQ * (NH + NKV) * 64) return;
    int i = t & 63;
    int h = (t >> 6) % (NH + NKV);
    int s = t / ((NH + NKV) * 64);
    int pos = max(ia[s], ib[s]) - 1;
    float* base = qkv + (size_t)s * QKV_N + (size_t)h * DH;
    float ang = (float)pos / powf(10000.0f, (float)i * 2.0f / (float)DH);
    float sn, c;
    sincosf(ang, &sn, &c);
    float x1 = base[i];
    float x2 = base[i + 64];
    base[i]      = x1 * c - x2 * sn;
    base[i + 64] = x2 * c + x1 * sn;
}

// ---------------------------------------------------------------------------
// Flash-decode attention, pass 1. Block per (s, kv, split); 4 waves = 4 q heads.
// DYNAMIC split ranges: split t covers [t*L/8, (t+1)*L/8) — balanced, no empty
// blocks. Unnormalized partial o + (m,l) to scratch. New-token K/V override.
// ---------------------------------------------------------------------------
__global__ __launch_bounds__(256) void attn_split(const float* __restrict__ qkv,
                                                  const float* __restrict__ k_cache,
                                                  const float* __restrict__ v_cache,
                                                  const int* __restrict__ ia,
                                                  const int* __restrict__ ib,
                                                  const int* __restrict__ block_tables,
                                                  float* __restrict__ po,
                                                  float* __restrict__ pm,
                                                  float* __restrict__ pl) {
    __shared__ float sc[GQ][TPS];   // 2 KB
    __shared__ float qs[GQ][DH];    // 2 KB
    __shared__ int   btl[NPAGES];

    int b  = blockIdx.x;
    int t  = b & 7;                 // split
    int kv = (b >> 3) & 7;
    int s  = b >> 6;
    int tid = threadIdx.x;
    int lane = tid & 63;
    int g = tid >> 6;

    int L   = max(ia[s], ib[s]);
    int pos = L - 1;
    int c_lo = (t * L) >> 3;        // balanced dynamic range
    int c_hi = ((t + 1) * L) >> 3;
    int n = c_hi - c_lo;            // 0..128

    if (tid < NPAGES) btl[tid] = block_tables[s * NPAGES + tid];
    for (int i = tid; i < GQ * DH; i += 256)
        qs[i >> 7][i & 127] = qkv[(size_t)s * QKV_N + (size_t)(kv * GQ) * DH + i]
                              * 0.08838834764831845f;
    __syncthreads();

    const float* knew = qkv + (size_t)s * QKV_N + (size_t)NH * DH + (size_t)kv * DH;
    const float* vnew = qkv + (size_t)s * QKV_N + (size_t)(NH + NKV) * DH + (size_t)kv * DH;
    const float4* q4 = (const float4*)qs[g];

    // Phase 1: scores (lane-per-token; <=2 iterations)
    for (int c = c_lo + lane; c < c_hi; c += 64) {
        const float* kr = (c == pos)
            ? knew
            : k_cache + ((size_t)btl[c >> 4] * BS + (c & 15)) * (size_t)(NKV * DH)
                      + (size_t)kv * DH;
        const float4* k4 = (const float4*)kr;
        float aa = 0.f, bb = 0.f, cc = 0.f, dd = 0.f;
        #pragma unroll
        for (int i = 0; i < 32; i += 4) {
            float4 k0 = k4[i], k1 = k4[i + 1], k2 = k4[i + 2], k3 = k4[i + 3];
            float4 q0 = q4[i], q1 = q4[i + 1], q2 = q4[i + 2], q3 = q4[i + 3];
            aa += q0.x * k0.x + q0.y * k0.y + q0.z * k0.z + q0.w * k0.w;
            bb += q1.x * k1.x + q1.y * k1.y + q1.z * k1.z + q1.w * k1.w;
            cc += q2.x * k2.x + q2.y * k2.y + q2.z * k2.z + q2.w * k2.w;
            dd += q3.x * k3.x + q3.y * k3.y + q3.z * k3.z + q3.w * k3.w;
        }
        sc[g][c - c_lo] = (aa + bb) + (cc + dd);
    }

    // Phase 2: wave softmax over sc[g][0..n)  (sc row is wave-private)
    float m = -1e30f;
    for (int c = lane; c < n; c += 64) m = fmaxf(m, sc[g][c]);
    #pragma unroll
    for (int off = 32; off; off >>= 1) m = fmaxf(m, __shfl_xor(m, off, 64));
    float l = 0.f;
    for (int c = lane; c < n; c += 64) {
        float p = expf(sc[g][c] - m);
        sc[g][c] = p;
        l += p;
    }
    #pragma unroll
    for (int off = 32; off; off >>= 1) l += __shfl_xor(l, off, 64);

    // Phase 3: unnormalized PV; lane owns dims (2*lane, 2*lane+1)
    float a0 = 0.f, a1 = 0.f, b0 = 0.f, b1 = 0.f;
    float c0 = 0.f, c1 = 0.f, e0 = 0.f, e1 = 0.f;
    int c = 0;
    for (; c + 3 < n; c += 4) {
        int cc0 = c_lo + c, cc1 = cc0 + 1, cc2 = cc0 + 2, cc3 = cc0 + 3;
        const float* v0p = (cc0 == pos) ? vnew : v_cache + ((size_t)btl[cc0 >> 4] * BS + (cc0 & 15)) * (size_t)(NKV * DH) + (size_t)kv * DH;
        const float* v1p = (cc1 == pos) ? vnew : v_cache + ((size_t)btl[cc1 >> 4] * BS + (cc1 & 15)) * (size_t)(NKV * DH) + (size_t)kv * DH;
        const float* v2p = (cc2 == pos) ? vnew : v_cache + ((size_t)btl[cc2 >> 4] * BS + (cc2 & 15)) * (size_t)(NKV * DH) + (size_t)kv * DH;
        const float* v3p = (cc3 == pos) ? vnew : v_cache + ((size_t)btl[cc3 >> 4] * BS + (cc3 & 15)) * (size_t)(NKV * DH) + (size_t)kv * DH;
        float p0 = sc[g][c], p1 = sc[g][c + 1], p2 = sc[g][c + 2], p3 = sc[g][c + 3];
        float2 v0 = ((const float2*)v0p)[lane];
        float2 v1 = ((const float2*)v1p)[lane];
        float2 v2 = ((const float2*)v2p)[lane];
        float2 v3 = ((const float2*)v3p)[lane];
        a0 = fmaf(p0, v0.x, a0); a1 = fmaf(p0, v0.y, a1);
        b0 = fmaf(p1, v1.x, b0); b1 = fmaf(p1, v1.y, b1);
        c0 = fmaf(p2, v2.x, c0); c1 = fmaf(p2, v2.y, c1);
        e0 = fmaf(p3, v3.x, e0); e1 = fmaf(p3, v3.y, e1);
    }
    for (; c < n; ++c) {
        int cc0 = c_lo + c;
        const float* vp = (cc0 == pos) ? vnew : v_cache + ((size_t)btl[cc0 >> 4] * BS + (cc0 & 15)) * (size_t)(NKV * DH) + (size_t)kv * DH;
        float p = sc[g][c];
        float2 v = ((const float2*)vp)[lane];
        a0 = fmaf(p, v.x, a0); a1 = fmaf(p, v.y, a1);
    }
    float o0 = (a0 + b0) + (c0 + e0);
    float o1 = (a1 + b1) + (c1 + e1);

    int hq = kv * GQ + g;
    int idx = t * NHQ + s * NH + hq;
    float* ob = po + (size_t)idx * DH;
    ob[2 * lane]     = o0;
    ob[2 * lane + 1] = o1;
    if (lane == 0) {
        pm[idx] = (n > 0) ? m : -1e30f;
        pl[idx] = (n > 0) ? l : 0.f;
    }
}

// ---------------------------------------------------------------------------
// Flash-decode combine over CSPLIT=8 splits. Block per (s,qh), thread per dim.
// ---------------------------------------------------------------------------
__global__ __launch_bounds__(128) void attn_combine(const float* __restrict__ po,
                                                    const float* __restrict__ pm,
                                                    const float* __restrict__ pl,
                                                    float* __restrict__ attn_out) {
    int sh = blockIdx.x;
    int d  = threadIdx.x;
    float mv[CSPLIT];
    float M = -1e30f;
    #pragma unroll
    for (int i = 0; i < CSPLIT; ++i) {
        mv[i] = pm[i * NHQ + sh];
        M = fmaxf(M, mv[i]);
    }
    float num = 0.f, denom = 0.f;
    #pragma unroll
    for (int i = 0; i < CSPLIT; ++i) {
        float w = expf(mv[i] - M);
        denom += pl[i * NHQ + sh] * w;
        num   += po[(size_t)(i * NHQ + sh) * DH + d] * w;
    }
    attn_out[(size_t)sh * DH + d] = num / denom;
}

// ---------------------------------------------------------------------------
extern "C" void kernel_launch(void* const* d_in, const int* in_sizes, int n_in,
                              void* d_out, int out_size, void* d_ws, size_t ws_size,
                              hipStream_t stream) {
    const float *hidden = nullptr, *k_cache = nullptr, *v_cache = nullptr;
    const float *qkv_w = nullptr, *o_w = nullptr;
    const int *i64a = nullptr, *i64b = nullptr, *block_tables = nullptr;
    for (int i = 0; i < n_in; ++i) {
        switch (in_sizes[i]) {
            case SEQ * HID:          hidden = (const float*)d_in[i]; break;
            case 4096 * BS * NKV * DH:
                if (!k_cache) k_cache = (const float*)d_in[i];
                else          v_cache = (const float*)d_in[i];
                break;
            case QKV_N * HID:        qkv_w = (const float*)d_in[i]; break;
            case HID * HID:          o_w   = (const float*)d_in[i]; break;
            case SEQ * NPAGES:       block_tables = (const int*)d_in[i]; break;
            case SEQ:
                if (!i64a) i64a = (const int*)d_in[i];
                else       i64b = (const int*)d_in[i];
                break;
        }
    }
    float* out = (float*)d_out;

    static float* qkv_p  = nullptr;
    static float* attn_p = nullptr;
    static float* part_p = nullptr;
    static float* po_p   = nullptr;
    static float* pm_p   = nullptr;
    static float* pl_p   = nullptr;
    if (!qkv_p) {
        void* p;
        hipGetSymbolAddress(&p, HIP_SYMBOL(g_qkv));  qkv_p  = (float*)p;
        hipGetSymbolAddress(&p, HIP_SYMBOL(g_attn)); attn_p = (float*)p;
        hipGetSymbolAddress(&p, HIP_SYMBOL(g_part)); part_p = (float*)p;
        hipGetSymbolAddress(&p, HIP_SYMBOL(g_po));   po_p   = (float*)p;
        hipGetSymbolAddress(&p, HIP_SYMBOL(g_pm));   pm_p   = (float*)p;
        hipGetSymbolAddress(&p, HIP_SYMBOL(g_pl));   pl_p   = (float*)p;
    }

    // 1) QKV projection
    gemm_tile<<<dim3(QKV_N / 64, KS), 256, 0, stream>>>(hidden, qkv_w, part_p,
                                                        QKV_N, HID);
    reduce_ks<<<(SEQ * QKV_N / 4 + 255) / 256, 256, 0, stream>>>(part_p, qkv_p,
                                                                 SEQ * QKV_N / 4);
    // 2) RoPE
    rope_scalar<<<(SEQ * (NH + NKV) * 64) / 256, 256, 0, stream>>>(qkv_p, i64a, i64b);
    // 3) Flash-decode attention (balanced dynamic splits)
    attn_split<<<SEQ * NKV * CSPLIT, 256, 0, stream>>>(qkv_p, k_cache, v_cache,
                                                       i64a, i64b, block_tables,
                                                       po_p, pm_p, pl_p);
    attn_combine<<<NHQ, 128, 0, stream>>>(po_p, pm_p, pl_p, attn_p);
    // 4) Output projection
    gemm_tile<<<dim3(HID / 64, KS), 256, 0, stream>>>(attn_p, o_w, part_p,
                                                      HID, HID);
    reduce_ks<<<(SEQ * HID / 4 + 255) / 256, 256, 0, stream>>>(part_p, out,
                                                               SEQ * HID / 4);
}

// Round 12
// 321.189 us; speedup vs baseline: 1.5057x; 1.1980x over previous
//
#include <hip/hip_runtime.h>
#include <math.h>

// Problem constants
#define HID 4096
#define NH  32
#define NKV 8
#define DH  128
#define SEQ 64
#define BS  16
#define MC  1024
#define QKV_N 6144                 // (NH + 2*NKV) * DH
#define NPAGES 64                  // MC / BS
#define KC  64                     // GEMM K-chunk (LDS tile depth)
#define KS  4                      // GEMM K-split factor
#define GQ  4                      // NH / NKV
#define CSPLIT 16                  // attention: fixed 64-token chunks
#define TPS 64                     // tokens per split
#define NHQ (SEQ * NH)             // 2048 (s,qhead) pairs

// Static device scratch (BSS) — immune to ws_size.
__device__ float g_qkv[SEQ * QKV_N];            // 1.5 MB
__device__ float g_attn[SEQ * HID];             // 1.0 MB
__device__ float g_part[KS * SEQ * QKV_N];      // 6.3 MB (GEMM partials)
__device__ float g_po[CSPLIT * NHQ * DH];       // 16.8 MB (attn o-partials)
__device__ float g_pm[CSPLIT * NHQ];
__device__ float g_pl[CSPLIT * NHQ];

// ---------------------------------------------------------------------------
// Tiled GEMM with K-split (unchanged, verified).
// ---------------------------------------------------------------------------
__global__ __launch_bounds__(256) void gemm_tile(const float* __restrict__ X,
                                                 const float* __restrict__ W,
                                                 float* __restrict__ P,
                                                 int N, int K) {
    __shared__ float Xs[KC][68];
    __shared__ float Ws[KC][68];
    const int tid = threadIdx.x;
    const int tx = tid & 15;
    const int ty = tid >> 4;
    const int jb = blockIdx.x * 64;
    const int ks = blockIdx.y;
    const int k_lo = ks * (K / KS);
    const int k_hi = k_lo + (K / KS);

    float4 a0 = {0,0,0,0}, a1 = {0,0,0,0}, a2 = {0,0,0,0}, a3 = {0,0,0,0};

    for (int k0 = k_lo; k0 < k_hi; k0 += KC) {
        #pragma unroll
        for (int r = 0; r < 4; ++r) {
            int idx = r * 256 + tid;
            int s  = idx >> 4;
            int k4 = idx & 15;
            float4 v = *(const float4*)(X + (size_t)s * K + k0 + k4 * 4);
            Xs[k4 * 4 + 0][s] = v.x;
            Xs[k4 * 4 + 1][s] = v.y;
            Xs[k4 * 4 + 2][s] = v.z;
            Xs[k4 * 4 + 3][s] = v.w;
        }
        #pragma unroll
        for (int r = 0; r < 4; ++r) {
            int idx = r * 256 + tid;
            int j  = idx >> 4;
            int k4 = idx & 15;
            float4 v = *(const float4*)(W + (size_t)(jb + j) * K + k0 + k4 * 4);
            Ws[k4 * 4 + 0][j] = v.x;
            Ws[k4 * 4 + 1][j] = v.y;
            Ws[k4 * 4 + 2][j] = v.z;
            Ws[k4 * 4 + 3][j] = v.w;
        }
        __syncthreads();
        #pragma unroll
        for (int kk = 0; kk < KC; ++kk) {
            float4 xv = *(const float4*)(&Xs[kk][ty * 4]);
            float4 wv = *(const float4*)(&Ws[kk][tx * 4]);
            a0.x = fmaf(xv.x, wv.x, a0.x); a0.y = fmaf(xv.x, wv.y, a0.y);
            a0.z = fmaf(xv.x, wv.z, a0.z); a0.w = fmaf(xv.x, wv.w, a0.w);
            a1.x = fmaf(xv.y, wv.x, a1.x); a1.y = fmaf(xv.y, wv.y, a1.y);
            a1.z = fmaf(xv.y, wv.z, a1.z); a1.w = fmaf(xv.y, wv.w, a1.w);
            a2.x = fmaf(xv.z, wv.x, a2.x); a2.y = fmaf(xv.z, wv.y, a2.y);
            a2.z = fmaf(xv.z, wv.z, a2.z); a2.w = fmaf(xv.z, wv.w, a2.w);
            a3.x = fmaf(xv.w, wv.x, a3.x); a3.y = fmaf(xv.w, wv.y, a3.y);
            a3.z = fmaf(xv.w, wv.z, a3.z); a3.w = fmaf(xv.w, wv.w, a3.w);
        }
        __syncthreads();
    }
    float* pb = P + (size_t)ks * SEQ * N;
    *(float4*)(pb + (size_t)(ty * 4 + 0) * N + jb + tx * 4) = a0;
    *(float4*)(pb + (size_t)(ty * 4 + 1) * N + jb + tx * 4) = a1;
    *(float4*)(pb + (size_t)(ty * 4 + 2) * N + jb + tx * 4) = a2;
    *(float4*)(pb + (size_t)(ty * 4 + 3) * N + jb + tx * 4) = a3;
}

__global__ __launch_bounds__(256) void reduce_ks(const float* __restrict__ P,
                                                 float* __restrict__ Y, int n4) {
    int t = blockIdx.x * 256 + threadIdx.x;
    if (t >= n4) return;
    const float4* p4 = (const float4*)P;
    float4 a = p4[t];
    float4 b = p4[t + n4];
    float4 c = p4[t + 2 * n4];
    float4 d = p4[t + 3 * n4];
    float4 r;
    r.x = (a.x + b.x) + (c.x + d.x);
    r.y = (a.y + b.y) + (c.y + d.y);
    r.z = (a.z + b.z) + (c.z + d.z);
    r.w = (a.w + b.w) + (c.w + d.w);
    ((float4*)Y)[t] = r;
}

// ---------------------------------------------------------------------------
// Scalar RoPE (unchanged, verified). sincosf(x, &sin, &cos) — sin FIRST.
// ---------------------------------------------------------------------------
__global__ __launch_bounds__(256) void rope_scalar(float* __restrict__ qkv,
                                                   const int* __restrict__ ia,
                                                   const int* __restrict__ ib) {
    int t = blockIdx.x * 256 + threadIdx.x;
    if (t >= SEQ * (NH + NKV) * 64) return;
    int i = t & 63;
    int h = (t >> 6) % (NH + NKV);
    int s = t / ((NH + NKV) * 64);
    int pos = max(ia[s], ib[s]) - 1;
    float* base = qkv + (size_t)s * QKV_N + (size_t)h * DH;
    float ang = (float)pos / powf(10000.0f, (float)i * 2.0f / (float)DH);
    float sn, c;
    sincosf(ang, &sn, &c);
    float x1 = base[i];
    float x2 = base[i + 64];
    base[i]      = x1 * c - x2 * sn;
    base[i + 64] = x2 * c + x1 * sn;
}

// ---------------------------------------------------------------------------
// Flash-decode attention pass 1, v3. Block per (s, kv, split); 4 waves = 4 q
// heads. FIXED 64-token chunks (uniform work quantum); splits past ceil(L/64)
// exit immediately. Phase 3 stages V through LDS in 16-token rounds for MLP.
// ---------------------------------------------------------------------------
__global__ __launch_bounds__(256) void attn_split(const float* __restrict__ qkv,
                                                  const float* __restrict__ k_cache,
                                                  const float* __restrict__ v_cache,
                                                  const int* __restrict__ ia,
                                                  const int* __restrict__ ib,
                                                  const int* __restrict__ block_tables,
                                                  float* __restrict__ po,
                                                  float* __restrict__ pm,
                                                  float* __restrict__ pl) {
    __shared__ float sc[GQ][TPS];    // 1 KB
    __shared__ float qs[GQ][DH];     // 2 KB
    __shared__ float Vlds[16][132];  // 8.25 KB (padded: stage-write conflicts)
    __shared__ int   btl[NPAGES];

    int b  = blockIdx.x;
    int t  = b & 15;                // split
    int kv = (b >> 4) & 7;
    int s  = b >> 7;
    int tid = threadIdx.x;
    int lane = tid & 63;
    int g = tid >> 6;

    int L   = max(ia[s], ib[s]);
    int pos = L - 1;
    int c_lo = t * TPS;
    int c_hi = min(c_lo + TPS, L);
    int n = c_hi - c_lo;            // block-uniform

    if (n <= 0) {                   // inactive split: record neutral (m,l), exit
        if (tid < GQ) {
            int idx = t * NHQ + s * NH + kv * GQ + tid;
            pm[idx] = -1e30f;
            pl[idx] = 0.f;
        }
        return;
    }

    if (tid < NPAGES) btl[tid] = block_tables[s * NPAGES + tid];
    for (int i = tid; i < GQ * DH; i += 256)
        qs[i >> 7][i & 127] = qkv[(size_t)s * QKV_N + (size_t)(kv * GQ) * DH + i]
                              * 0.08838834764831845f;
    __syncthreads();

    const float* knew = qkv + (size_t)s * QKV_N + (size_t)NH * DH + (size_t)kv * DH;
    const float* vnew = qkv + (size_t)s * QKV_N + (size_t)(NH + NKV) * DH + (size_t)kv * DH;
    const float4* q4 = (const float4*)qs[g];

    // Phase 1: scores, lane-per-token (single iteration, n <= 64)
    {
        int c = c_lo + lane;
        if (c < c_hi) {
            const float* kr = (c == pos)
                ? knew
                : k_cache + ((size_t)btl[c >> 4] * BS + (c & 15)) * (size_t)(NKV * DH)
                          + (size_t)kv * DH;
            const float4* k4 = (const float4*)kr;
            float aa = 0.f, bb = 0.f, cc = 0.f, dd = 0.f;
            #pragma unroll
            for (int i = 0; i < 32; i += 4) {
                float4 k0 = k4[i], k1 = k4[i + 1], k2 = k4[i + 2], k3 = k4[i + 3];
                float4 q0 = q4[i], q1 = q4[i + 1], q2 = q4[i + 2], q3 = q4[i + 3];
                aa += q0.x * k0.x + q0.y * k0.y + q0.z * k0.z + q0.w * k0.w;
                bb += q1.x * k1.x + q1.y * k1.y + q1.z * k1.z + q1.w * k1.w;
                cc += q2.x * k2.x + q2.y * k2.y + q2.z * k2.z + q2.w * k2.w;
                dd += q3.x * k3.x + q3.y * k3.y + q3.z * k3.z + q3.w * k3.w;
            }
            sc[g][lane] = (aa + bb) + (cc + dd);
        }
    }

    // Phase 2: wave softmax over sc[g][0..n)   (sc row is wave-private)
    float m = -1e30f;
    if (lane < n) m = sc[g][lane];
    #pragma unroll
    for (int off = 32; off; off >>= 1) m = fmaxf(m, __shfl_xor(m, off, 64));
    float l = 0.f;
    if (lane < n) {
        float p = expf(sc[g][lane] - m);
        sc[g][lane] = p;
        l = p;
    }
    #pragma unroll
    for (int off = 32; off; off >>= 1) l += __shfl_xor(l, off, 64);
    __syncthreads();   // sc[g][*] must be visible to whole block? (wave-private rows; sync orders Vlds reuse anyway)

    // Phase 3: PV via LDS-staged V, 16-token rounds. lane owns dims 2l, 2l+1.
    float o0 = 0.f, o1 = 0.f;
    const int row = tid >> 4;       // 0..15 (staging role)
    const int qv  = tid & 15;
    for (int r = 0; r < 4; ++r) {
        int base = r * 16;
        if (base >= n) break;
        int ct = c_lo + base + row;
        if (ct < c_hi) {
            const float* vr = (ct == pos)
                ? vnew
                : v_cache + ((size_t)btl[ct >> 4] * BS + (ct & 15)) * (size_t)(NKV * DH)
                          + (size_t)kv * DH;
            const float4* v4 = (const float4*)vr;
            float4 va = v4[qv * 2];
            float4 vb = v4[qv * 2 + 1];
            *(float4*)(&Vlds[row][qv * 8])     = va;
            *(float4*)(&Vlds[row][qv * 8 + 4]) = vb;
        }
        __syncthreads();
        int cnt = min(16, n - base);
        #pragma unroll 4
        for (int tt = 0; tt < cnt; ++tt) {
            float p = sc[g][base + tt];
            float2 v = *(const float2*)(&Vlds[tt][2 * lane]);
            o0 = fmaf(p, v.x, o0);
            o1 = fmaf(p, v.y, o1);
        }
        __syncthreads();
    }

    int idx = t * NHQ + s * NH + kv * GQ + g;
    float* ob = po + (size_t)idx * DH;
    ob[2 * lane]     = o0;
    ob[2 * lane + 1] = o1;
    if (lane == 0) {
        pm[idx] = m;
        pl[idx] = l;
    }
}

// ---------------------------------------------------------------------------
// Flash-decode combine over CSPLIT=16 splits. Block per (s,qh), thread per dim.
// ---------------------------------------------------------------------------
__global__ __launch_bounds__(128) void attn_combine(const float* __restrict__ po,
                                                    const float* __restrict__ pm,
                                                    const float* __restrict__ pl,
                                                    float* __restrict__ attn_out) {
    int sh = blockIdx.x;
    int d  = threadIdx.x;
    float mv[CSPLIT];
    float M = -1e30f;
    #pragma unroll
    for (int i = 0; i < CSPLIT; ++i) {
        mv[i] = pm[i * NHQ + sh];
        M = fmaxf(M, mv[i]);
    }
    float num = 0.f, denom = 0.f;
    #pragma unroll
    for (int i = 0; i < CSPLIT; ++i) {
        float w = expf(mv[i] - M);   // 0 for inactive splits (mv=-1e30)
        denom += pl[i * NHQ + sh] * w;
        num   += po[(size_t)(i * NHQ + sh) * DH + d] * w;
    }
    attn_out[(size_t)sh * DH + d] = num / denom;
}

// ---------------------------------------------------------------------------
extern "C" void kernel_launch(void* const* d_in, const int* in_sizes, int n_in,
                              void* d_out, int out_size, void* d_ws, size_t ws_size,
                              hipStream_t stream) {
    const float *hidden = nullptr, *k_cache = nullptr, *v_cache = nullptr;
    const float *qkv_w = nullptr, *o_w = nullptr;
    const int *i64a = nullptr, *i64b = nullptr, *block_tables = nullptr;
    for (int i = 0; i < n_in; ++i) {
        switch (in_sizes[i]) {
            case SEQ * HID:          hidden = (const float*)d_in[i]; break;
            case 4096 * BS * NKV * DH:
                if (!k_cache) k_cache = (const float*)d_in[i];
                else          v_cache = (const float*)d_in[i];
                break;
            case QKV_N * HID:        qkv_w = (const float*)d_in[i]; break;
            case HID * HID:          o_w   = (const float*)d_in[i]; break;
            case SEQ * NPAGES:       block_tables = (const int*)d_in[i]; break;
            case SEQ:
                if (!i64a) i64a = (const int*)d_in[i];
                else       i64b = (const int*)d_in[i];
                break;
        }
    }
    float* out = (float*)d_out;

    static float* qkv_p  = nullptr;
    static float* attn_p = nullptr;
    static float* part_p = nullptr;
    static float* po_p   = nullptr;
    static float* pm_p   = nullptr;
    static float* pl_p   = nullptr;
    if (!qkv_p) {
        void* p;
        hipGetSymbolAddress(&p, HIP_SYMBOL(g_qkv));  qkv_p  = (float*)p;
        hipGetSymbolAddress(&p, HIP_SYMBOL(g_attn)); attn_p = (float*)p;
        hipGetSymbolAddress(&p, HIP_SYMBOL(g_part)); part_p = (float*)p;
        hipGetSymbolAddress(&p, HIP_SYMBOL(g_po));   po_p   = (float*)p;
        hipGetSymbolAddress(&p, HIP_SYMBOL(g_pm));   pm_p   = (float*)p;
        hipGetSymbolAddress(&p, HIP_SYMBOL(g_pl));   pl_p   = (float*)p;
    }

    // 1) QKV projection
    gemm_tile<<<dim3(QKV_N / 64, KS), 256, 0, stream>>>(hidden, qkv_w, part_p,
                                                        QKV_N, HID);
    reduce_ks<<<(SEQ * QKV_N / 4 + 255) / 256, 256, 0, stream>>>(part_p, qkv_p,
                                                                 SEQ * QKV_N / 4);
    // 2) RoPE
    rope_scalar<<<(SEQ * (NH + NKV) * 64) / 256, 256, 0, stream>>>(qkv_p, i64a, i64b);
    // 3) Flash-decode attention (fixed 64-token chunks, 16 splits)
    attn_split<<<SEQ * NKV * CSPLIT, 256, 0, stream>>>(qkv_p, k_cache, v_cache,
                                                       i64a, i64b, block_tables,
                                                       po_p, pm_p, pl_p);
    attn_combine<<<NHQ, 128, 0, stream>>>(po_p, pm_p, pl_p, attn_p);
    // 4) Output projection
    gemm_tile<<<dim3(HID / 64, KS), 256, 0, stream>>>(attn_p, o_w, part_p,
                                                      HID, HID);
    reduce_ks<<<(SEQ * HID / 4 + 255) / 256, 256, 0, stream>>>(part_p, out,
                                                               SEQ * HID / 4);
}